// Round 17
// baseline (35.840 us; speedup 1.0000x reference)
//
#include <hip/hip_runtime.h>
#include <hip/hip_bf16.h>

#define NOBJ 25

typedef short bf16x8 __attribute__((ext_vector_type(8)));
typedef short s16x4 __attribute__((ext_vector_type(4)));
typedef float f32x4 __attribute__((ext_vector_type(4)));
typedef unsigned int uint;

__device__ __forceinline__ short f2bf(float f) {
  __hip_bfloat16 b = __float2bfloat16(f);  // RTN
  return *reinterpret_cast<short*>(&b);
}
__device__ __forceinline__ float bf2f(short s) {
  unsigned u = ((unsigned)(unsigned short)s) << 16;
  return __uint_as_float(u);
}
__device__ __forceinline__ uint packhl(float v) {
  const short hi = f2bf(v);
  const short lo = f2bf(v - bf2f(hi));
  return ((uint)(unsigned short)hi << 16) | (uint)(unsigned short)lo;
}

// ---------------------------------------------------------------------------
// K1: blocks 0..127 MLP-weight prep; 128..639 conv (R16 structure).
// CHANGE vs R16 (single variable): pairwise uses the relu split
// relu(x) = (x+|x|)/2 -> Sum w*relu = 0.5*(separable linear part computed
// via running prefix/suffix scalars) + 0.5*Sum w*|x| (2 VALU/term via the
// free |x| source modifier). ~730 ops/lane vs 900.
// ---------------------------------------------------------------------------
__global__ __launch_bounds__(256, 2) void conv_prep_kernel(
    const float* __restrict__ x,    // (1024, 25*64)
    const float* __restrict__ cw0,  // (256, 64)
    const float* __restrict__ cw1,  // (256, 64)
    const float* __restrict__ cb,   // (256)
    const float* __restrict__ w1, const float* __restrict__ w2,
    const float* __restrict__ w3,
    uint* __restrict__ h0p,         // (1024, 256) packed hi|lo bf16
    short* __restrict__ wfm)        // 270336 shorts, fragment-linear hi/lo
{
  __shared__ short xs[2][32][72];        // 9216 B
  __shared__ float ab[4][2][NOBJ][68];   // 54400 B (per-wave scratch)

  if (blockIdx.x < 128) {
    for (int j = blockIdx.x * 256 + threadIdx.x; j < 270336; j += 128 * 256) {
      const float* w; int term, f, nt;
      const bool isw3 = (j >= 262144);
      if (!isw3) {
        w = (j >> 17) ? w2 : w1;
        const int idx = j & 131071;
        term = idx >> 16; f = idx & 65535; nt = f >> 12;
      } else {
        w = w3;
        const int idx = j - 262144;  // 0..8191
        term = idx >> 12; f = idx & 4095; nt = 0;
      }
      const int ks = (f >> 9) & 7;
      const int l  = (f >> 3) & 63;
      const int jj = f & 7;
      const int col = nt * 16 + (l & 15);
      const int k   = ks * 32 + (l >> 4) * 8 + jj;
      const float v = (isw3 && col >= 10) ? 0.f : w[col * 256 + k];
      const short hi = f2bf(v);
      wfm[j] = (term == 0) ? hi : f2bf(v - bf2f(hi));
    }
    return;
  }

  // ---- conv branch ----
  const int t = threadIdx.x;
  const int lane = t & 63;
  const int wv = t >> 6;
  const int r = lane & 15;
  const int g = lane >> 4;
  const int n0 = (blockIdx.x - 128) * 2;

  // x staging first (cold misses issued early)
  for (int s = 0; s < 2; ++s) {
    const float4* xg = reinterpret_cast<const float4*>(x + (size_t)(n0 + s) * (NOBJ * 64));
    for (int i = t; i < 400; i += 256) {
      float4 v = xg[i];
      s16x4 p;
      p.x = f2bf(v.x); p.y = f2bf(v.y); p.z = f2bf(v.z); p.w = f2bf(v.w);
      *reinterpret_cast<s16x4*>(&xs[s][i >> 4][(i & 15) * 4]) = p;
    }
  }

  bf16x8 Wf[2][4][2];  // [tap][ntile][kstep]
#pragma unroll
  for (int tap = 0; tap < 2; ++tap) {
    const float* wsrc = tap ? cw1 : cw0;
#pragma unroll
    for (int ntl = 0; ntl < 4; ++ntl)
#pragma unroll
      for (int ks = 0; ks < 2; ++ks) {
        const int ch = wv * 64 + ntl * 16 + r;
        const float* p = wsrc + ch * 64 + ks * 32 + g * 8;
        const float4 a = *reinterpret_cast<const float4*>(p);
        const float4 b = *reinterpret_cast<const float4*>(p + 4);
        bf16x8 fr;
        fr[0] = f2bf(a.x); fr[1] = f2bf(a.y); fr[2] = f2bf(a.z); fr[3] = f2bf(a.w);
        fr[4] = f2bf(b.x); fr[5] = f2bf(b.y); fr[6] = f2bf(b.z); fr[7] = f2bf(b.w);
        Wf[tap][ntl][ks] = fr;
      }
  }
  float cbv[4];
#pragma unroll
  for (int ntl = 0; ntl < 4; ++ntl) cbv[ntl] = cb[wv * 64 + ntl * 16 + r];

  __syncthreads();

  for (int s = 0; s < 2; ++s) {
    bf16x8 Xf[2][2];  // rows 25..31 garbage, outputs unread
#pragma unroll
    for (int mt = 0; mt < 2; ++mt)
#pragma unroll
      for (int ks = 0; ks < 2; ++ks)
        Xf[mt][ks] = *reinterpret_cast<const bf16x8*>(&xs[s][mt * 16 + r][ks * 32 + g * 8]);

    f32x4 acc[2][2][4];  // [tap][mtile][ntile]
#pragma unroll
    for (int tap = 0; tap < 2; ++tap)
#pragma unroll
      for (int mt = 0; mt < 2; ++mt)
#pragma unroll
        for (int ntl = 0; ntl < 4; ++ntl) {
          f32x4 z = {0.f, 0.f, 0.f, 0.f};
          acc[tap][mt][ntl] = z;
        }

#pragma unroll
    for (int tap = 0; tap < 2; ++tap)
#pragma unroll
      for (int mt = 0; mt < 2; ++mt)
#pragma unroll
        for (int ntl = 0; ntl < 4; ++ntl)
#pragma unroll
          for (int ks = 0; ks < 2; ++ks)
            acc[tap][mt][ntl] = __builtin_amdgcn_mfma_f32_16x16x32_bf16(
                Xf[mt][ks], Wf[tap][ntl][ks], acc[tap][mt][ntl], 0, 0, 0);

#pragma unroll
    for (int tap = 0; tap < 2; ++tap)
#pragma unroll
      for (int mt = 0; mt < 2; ++mt)
#pragma unroll
        for (int ntl = 0; ntl < 4; ++ntl) {
          const int cl = ntl * 16 + r;
          const int row0 = mt * 16 + g * 4;
          const float badd = (tap == 0) ? cbv[ntl] : 0.f;
#pragma unroll
          for (int q = 0; q < 4; ++q)
            if (row0 + q < NOBJ) ab[wv][tap][row0 + q][cl] = acc[tap][mt][ntl][q] + badd;
        }
    // same-wave LDS RAW ordered by lgkmcnt; ab wave-private -> no barrier

    float A[NOBJ], Bv[NOBJ];
#pragma unroll
    for (int i = 0; i < NOBJ; ++i) { A[i] = ab[wv][0][i][lane]; Bv[i] = ab[wv][1][i][lane]; }

    // relu split: sum_d w_d sum_i relu(A_i + B_{i+d})
    //   = 0.5*[ sum_d w_d (prefA(24-d) + sufB(d)) + sum_d w_d sum_i |A_i+B_{i+d}| ]
    float pa = A[0], qb = Bv[NOBJ - 1];
    float lin = 0.f, absacc = 0.f;
#pragma unroll
    for (int dd = NOBJ - 1; dd >= 1; --dd) {
      const float w = 1.0f / (float)(NOBJ - dd);
      lin = __builtin_fmaf(pa + qb, w, lin);
      float sd = 0.f;
#pragma unroll
      for (int i = 0; i + dd < NOBJ; ++i)
        sd += __builtin_fabsf(A[i] + Bv[i + dd]);   // add + add-with-|x| mod
      absacc = __builtin_fmaf(sd, w, absacc);
      if (dd > 1) { pa += A[NOBJ - dd]; qb += Bv[dd - 1]; }
    }
    const float hacc = (lin + absacc) * (0.5f / (float)(NOBJ - 1));
    h0p[(size_t)(n0 + s) * 256 + t] = packhl(hacc);
  }
}

// ---------------------------------------------------------------------------
// K2 (R16 verbatim): full 3-layer MLP. 64 blocks x 1024 threads (16 waves =
// 4 waves/SIMD). Wave wv owns one 16-col tile; Hs hi/lo ping-pong in LDS.
// ---------------------------------------------------------------------------
__global__ __launch_bounds__(1024, 4) void mlp_fused(
    const uint* __restrict__ inp,   // (1024,256) packed hi|lo
    const short* __restrict__ wf,   // fragment-linear hi/lo weights
    const float* __restrict__ b1, const float* __restrict__ b2,
    const float* __restrict__ b3,
    float* __restrict__ out)        // (1024, 10)
{
  __shared__ short Hs[2][2][16][272];  // [pp][term][row][k] 34816 B
  const int t = threadIdx.x, lane = t & 63, wv = t >> 6;
  const int r = lane & 15, g = lane >> 4;
  const int m0 = blockIdx.x * 16;

  {
    const uint4 u = (reinterpret_cast<const uint4*>(inp) + m0 * 64)[t];
    const int row = t >> 6, c = (t & 63) * 4;
    s16x4 hi4, lo4;
    hi4.x = (short)(u.x >> 16); lo4.x = (short)(u.x & 0xffff);
    hi4.y = (short)(u.y >> 16); lo4.y = (short)(u.y & 0xffff);
    hi4.z = (short)(u.z >> 16); lo4.z = (short)(u.z & 0xffff);
    hi4.w = (short)(u.w >> 16); lo4.w = (short)(u.w & 0xffff);
    *reinterpret_cast<s16x4*>(&Hs[0][0][row][c]) = hi4;
    *reinterpret_cast<s16x4*>(&Hs[0][1][row][c]) = lo4;
  }
  __syncthreads();

  int pp = 0;
  const float* bias[2] = {b1, b2};
#pragma unroll
  for (int L = 0; L < 2; ++L) {
    const short* wl = wf + L * 131072;

    bf16x8 bh[8], bl[8];
#pragma unroll
    for (int ks = 0; ks < 8; ++ks) {
      bh[ks] = *reinterpret_cast<const bf16x8*>(wl + ((wv * 8 + ks) << 9) + lane * 8);
      bl[ks] = *reinterpret_cast<const bf16x8*>(wl + 65536 + ((wv * 8 + ks) << 9) + lane * 8);
    }
    bf16x8 ahi[8];
#pragma unroll
    for (int ks = 0; ks < 8; ++ks)
      ahi[ks] = *reinterpret_cast<const bf16x8*>(&Hs[pp][0][r][ks * 32 + g * 8]);

    const float bv = bias[L][wv * 16 + r];
    f32x4 acc = {bv, bv, bv, bv};
#pragma unroll
    for (int ks = 0; ks < 8; ++ks) {
      const bf16x8 alo = *reinterpret_cast<const bf16x8*>(&Hs[pp][1][r][ks * 32 + g * 8]);
      acc = __builtin_amdgcn_mfma_f32_16x16x32_bf16(ahi[ks], bh[ks], acc, 0, 0, 0);
      acc = __builtin_amdgcn_mfma_f32_16x16x32_bf16(alo, bh[ks], acc, 0, 0, 0);
      acc = __builtin_amdgcn_mfma_f32_16x16x32_bf16(ahi[ks], bl[ks], acc, 0, 0, 0);
    }

    const int col = wv * 16 + r;
#pragma unroll
    for (int q = 0; q < 4; ++q) {
      const float v = fmaxf(acc[q], 0.f);
      const int row = 4 * g + q;
      const short hi = f2bf(v);
      Hs[pp ^ 1][0][row][col] = hi;
      Hs[pp ^ 1][1][row][col] = f2bf(v - bf2f(hi));
    }
    __syncthreads();
    pp ^= 1;
  }

  // layer 3: one 16x16 tile (cols 10..15 zero-padded), wave 0 only
  if (wv == 0) {
    const float bv = (r < 10) ? b3[r] : 0.f;
    f32x4 acc = {bv, bv, bv, bv};
    bf16x8 ahi[8], alo[8], bh[8], bl[8];
#pragma unroll
    for (int ks = 0; ks < 8; ++ks) {
      const int ko = ks * 32 + g * 8;
      ahi[ks] = *reinterpret_cast<const bf16x8*>(&Hs[pp][0][r][ko]);
      alo[ks] = *reinterpret_cast<const bf16x8*>(&Hs[pp][1][r][ko]);
      bh[ks] = *reinterpret_cast<const bf16x8*>(wf + 262144 + (ks << 9) + lane * 8);
      bl[ks] = *reinterpret_cast<const bf16x8*>(wf + 262144 + 4096 + (ks << 9) + lane * 8);
    }
#pragma unroll
    for (int ks = 0; ks < 8; ++ks) {
      acc = __builtin_amdgcn_mfma_f32_16x16x32_bf16(ahi[ks], bh[ks], acc, 0, 0, 0);
      acc = __builtin_amdgcn_mfma_f32_16x16x32_bf16(alo[ks], bh[ks], acc, 0, 0, 0);
      acc = __builtin_amdgcn_mfma_f32_16x16x32_bf16(ahi[ks], bl[ks], acc, 0, 0, 0);
    }
    if (r < 10) {
#pragma unroll
      for (int q = 0; q < 4; ++q)
        out[(size_t)(m0 + 4 * g + q) * 10 + r] = acc[q];
    }
  }
}

extern "C" void kernel_launch(void* const* d_in, const int* in_sizes, int n_in,
                              void* d_out, int out_size, void* d_ws, size_t ws_size,
                              hipStream_t stream) {
  const float* x   = (const float*)d_in[0];
  const float* cw0 = (const float*)d_in[1];
  const float* cw1 = (const float*)d_in[2];
  const float* cb  = (const float*)d_in[3];
  const float* w1  = (const float*)d_in[4];
  const float* b1  = (const float*)d_in[5];
  const float* w2  = (const float*)d_in[6];
  const float* b2  = (const float*)d_in[7];
  const float* w3  = (const float*)d_in[8];
  const float* b3  = (const float*)d_in[9];
  float* out = (float*)d_out;

  uint* h0p = (uint*)d_ws;             // 1 MB packed hi|lo
  short* wfm = (short*)(h0p + 262144); // 540 KB frag-linear weights

  conv_prep_kernel<<<640, 256, 0, stream>>>(x, cw0, cw1, cb, w1, w2, w3, h0p, wfm);
  mlp_fused<<<64, 1024, 0, stream>>>(h0p, wfm, b1, b2, b3, out);
}

// Round 18
// 32.074 us; speedup vs baseline: 1.1174x; 1.1174x over previous
//
#include <hip/hip_runtime.h>
#include <hip/hip_bf16.h>

#define NOBJ 25

typedef short bf16x8 __attribute__((ext_vector_type(8)));
typedef short s16x4 __attribute__((ext_vector_type(4)));
typedef float f32x4 __attribute__((ext_vector_type(4)));
typedef unsigned int uint;

__device__ __forceinline__ short f2bf(float f) {
  __hip_bfloat16 b = __float2bfloat16(f);  // RTN
  return *reinterpret_cast<short*>(&b);
}
__device__ __forceinline__ float bf2f(short s) {
  unsigned u = ((unsigned)(unsigned short)s) << 16;
  return __uint_as_float(u);
}
__device__ __forceinline__ uint packhl(float v) {
  const short hi = f2bf(v);
  const short lo = f2bf(v - bf2f(hi));
  return ((uint)(unsigned short)hi << 16) | (uint)(unsigned short)lo;
}

// ---------------------------------------------------------------------------
// K1: 512 blocks exactly (= one 2-block/CU residency round; the R5..R17
// versions used 640+ blocks -> ceil(640/512) = 2 sequential block-rounds,
// a hidden ~2x on the conv kernel). Each block:
//   (a) grid-strided 1/512 share of MLP-weight prep (~2.1 elem/thread),
//       overlapping its cold w-loads with (b)'s cold x misses;
//   (b) conv for samples 2*bid, 2*bid+1 (R13/R16-verbatim body).
// ---------------------------------------------------------------------------
__global__ __launch_bounds__(256, 2) void conv_prep_kernel(
    const float* __restrict__ x,    // (1024, 25*64)
    const float* __restrict__ cw0,  // (256, 64)
    const float* __restrict__ cw1,  // (256, 64)
    const float* __restrict__ cb,   // (256)
    const float* __restrict__ w1, const float* __restrict__ w2,
    const float* __restrict__ w3,
    uint* __restrict__ h0p,         // (1024, 256) packed hi|lo bf16
    short* __restrict__ wfm)        // 270336 shorts, fragment-linear hi/lo
{
  __shared__ short xs[2][32][72];        // 9216 B
  __shared__ float ab[4][2][NOBJ][68];   // 54400 B (per-wave scratch)

  const int t = threadIdx.x;
  const int lane = t & 63;
  const int wv = t >> 6;
  const int r = lane & 15;
  const int g = lane >> 4;
  const int n0 = blockIdx.x * 2;

  // ---- x staging first: cold HBM misses issued before anything else ----
  for (int s = 0; s < 2; ++s) {
    const float4* xg = reinterpret_cast<const float4*>(x + (size_t)(n0 + s) * (NOBJ * 64));
    for (int i = t; i < 400; i += 256) {
      float4 v = xg[i];
      s16x4 p;
      p.x = f2bf(v.x); p.y = f2bf(v.y); p.z = f2bf(v.z); p.w = f2bf(v.w);
      *reinterpret_cast<s16x4*>(&xs[s][i >> 4][(i & 15) * 4]) = p;
    }
  }

  // ---- inline prep share: layer L at L*131072: [term][nt][ks][lane][j];
  // layer 3 at 262144: [term][ks][lane][j], cols>=10 zero-padded.
  // value = w[(nt*16+(lane&15))*256 + ks*32 + (lane>>4)*8 + j]
  for (int j = blockIdx.x * 256 + t; j < 270336; j += 512 * 256) {
    const float* w; int term, f, nt;
    const bool isw3 = (j >= 262144);
    if (!isw3) {
      w = (j >> 17) ? w2 : w1;
      const int idx = j & 131071;
      term = idx >> 16; f = idx & 65535; nt = f >> 12;
    } else {
      w = w3;
      const int idx = j - 262144;  // 0..8191
      term = idx >> 12; f = idx & 4095; nt = 0;
    }
    const int ks = (f >> 9) & 7;
    const int l  = (f >> 3) & 63;
    const int jj = f & 7;
    const int col = nt * 16 + (l & 15);
    const int k   = ks * 32 + (l >> 4) * 8 + jj;
    const float v = (isw3 && col >= 10) ? 0.f : w[col * 256 + k];
    const short hi = f2bf(v);
    wfm[j] = (term == 0) ? hi : f2bf(v - bf2f(hi));
  }

  // ---- conv W fragments (overlaps remaining staging misses) ----
  bf16x8 Wf[2][4][2];  // [tap][ntile][kstep]
#pragma unroll
  for (int tap = 0; tap < 2; ++tap) {
    const float* wsrc = tap ? cw1 : cw0;
#pragma unroll
    for (int ntl = 0; ntl < 4; ++ntl)
#pragma unroll
      for (int ks = 0; ks < 2; ++ks) {
        const int ch = wv * 64 + ntl * 16 + r;
        const float* p = wsrc + ch * 64 + ks * 32 + g * 8;
        const float4 a = *reinterpret_cast<const float4*>(p);
        const float4 b = *reinterpret_cast<const float4*>(p + 4);
        bf16x8 fr;
        fr[0] = f2bf(a.x); fr[1] = f2bf(a.y); fr[2] = f2bf(a.z); fr[3] = f2bf(a.w);
        fr[4] = f2bf(b.x); fr[5] = f2bf(b.y); fr[6] = f2bf(b.z); fr[7] = f2bf(b.w);
        Wf[tap][ntl][ks] = fr;
      }
  }
  float cbv[4];
#pragma unroll
  for (int ntl = 0; ntl < 4; ++ntl) cbv[ntl] = cb[wv * 64 + ntl * 16 + r];

  __syncthreads();

  for (int s = 0; s < 2; ++s) {
    bf16x8 Xf[2][2];  // rows 25..31 garbage, outputs unread
#pragma unroll
    for (int mt = 0; mt < 2; ++mt)
#pragma unroll
      for (int ks = 0; ks < 2; ++ks)
        Xf[mt][ks] = *reinterpret_cast<const bf16x8*>(&xs[s][mt * 16 + r][ks * 32 + g * 8]);

    f32x4 acc[2][2][4];  // [tap][mtile][ntile]
#pragma unroll
    for (int tap = 0; tap < 2; ++tap)
#pragma unroll
      for (int mt = 0; mt < 2; ++mt)
#pragma unroll
        for (int ntl = 0; ntl < 4; ++ntl) {
          f32x4 z = {0.f, 0.f, 0.f, 0.f};
          acc[tap][mt][ntl] = z;
        }

#pragma unroll
    for (int tap = 0; tap < 2; ++tap)
#pragma unroll
      for (int mt = 0; mt < 2; ++mt)
#pragma unroll
        for (int ntl = 0; ntl < 4; ++ntl)
#pragma unroll
          for (int ks = 0; ks < 2; ++ks)
            acc[tap][mt][ntl] = __builtin_amdgcn_mfma_f32_16x16x32_bf16(
                Xf[mt][ks], Wf[tap][ntl][ks], acc[tap][mt][ntl], 0, 0, 0);

#pragma unroll
    for (int tap = 0; tap < 2; ++tap)
#pragma unroll
      for (int mt = 0; mt < 2; ++mt)
#pragma unroll
        for (int ntl = 0; ntl < 4; ++ntl) {
          const int cl = ntl * 16 + r;
          const int row0 = mt * 16 + g * 4;
          const float badd = (tap == 0) ? cbv[ntl] : 0.f;
#pragma unroll
          for (int q = 0; q < 4; ++q)
            if (row0 + q < NOBJ) ab[wv][tap][row0 + q][cl] = acc[tap][mt][ntl][q] + badd;
        }
    // same-wave LDS RAW ordered by lgkmcnt; ab wave-private -> no barrier

    float A[NOBJ], Bv[NOBJ];
#pragma unroll
    for (int i = 0; i < NOBJ; ++i) { A[i] = ab[wv][0][i][lane]; Bv[i] = ab[wv][1][i][lane]; }
    float hacc = 0.f;
#pragma unroll
    for (int d = 1; d < NOBJ; ++d) {
      float sd = 0.f;
#pragma unroll
      for (int i = 0; i + d < NOBJ; ++i) sd += fmaxf(A[i] + Bv[i + d], 0.f);
      hacc = __builtin_fmaf(sd, 1.0f / (float)(NOBJ - d), hacc);
    }
    h0p[(size_t)(n0 + s) * 256 + t] = packhl(hacc * (1.0f / (float)(NOBJ - 1)));
  }
}

// ---------------------------------------------------------------------------
// K2 (R16 verbatim): full 3-layer MLP. 64 blocks x 1024 threads (16 waves =
// 4 waves/SIMD). Wave wv owns one 16-col tile; Hs hi/lo ping-pong in LDS.
// ---------------------------------------------------------------------------
__global__ __launch_bounds__(1024, 4) void mlp_fused(
    const uint* __restrict__ inp,   // (1024,256) packed hi|lo
    const short* __restrict__ wf,   // fragment-linear hi/lo weights
    const float* __restrict__ b1, const float* __restrict__ b2,
    const float* __restrict__ b3,
    float* __restrict__ out)        // (1024, 10)
{
  __shared__ short Hs[2][2][16][272];  // [pp][term][row][k] 34816 B
  const int t = threadIdx.x, lane = t & 63, wv = t >> 6;
  const int r = lane & 15, g = lane >> 4;
  const int m0 = blockIdx.x * 16;

  {
    const uint4 u = (reinterpret_cast<const uint4*>(inp) + m0 * 64)[t];
    const int row = t >> 6, c = (t & 63) * 4;
    s16x4 hi4, lo4;
    hi4.x = (short)(u.x >> 16); lo4.x = (short)(u.x & 0xffff);
    hi4.y = (short)(u.y >> 16); lo4.y = (short)(u.y & 0xffff);
    hi4.z = (short)(u.z >> 16); lo4.z = (short)(u.z & 0xffff);
    hi4.w = (short)(u.w >> 16); lo4.w = (short)(u.w & 0xffff);
    *reinterpret_cast<s16x4*>(&Hs[0][0][row][c]) = hi4;
    *reinterpret_cast<s16x4*>(&Hs[0][1][row][c]) = lo4;
  }
  __syncthreads();

  int pp = 0;
  const float* bias[2] = {b1, b2};
#pragma unroll
  for (int L = 0; L < 2; ++L) {
    const short* wl = wf + L * 131072;

    bf16x8 bh[8], bl[8];
#pragma unroll
    for (int ks = 0; ks < 8; ++ks) {
      bh[ks] = *reinterpret_cast<const bf16x8*>(wl + ((wv * 8 + ks) << 9) + lane * 8);
      bl[ks] = *reinterpret_cast<const bf16x8*>(wl + 65536 + ((wv * 8 + ks) << 9) + lane * 8);
    }
    bf16x8 ahi[8];
#pragma unroll
    for (int ks = 0; ks < 8; ++ks)
      ahi[ks] = *reinterpret_cast<const bf16x8*>(&Hs[pp][0][r][ks * 32 + g * 8]);

    const float bv = bias[L][wv * 16 + r];
    f32x4 acc = {bv, bv, bv, bv};
#pragma unroll
    for (int ks = 0; ks < 8; ++ks) {
      const bf16x8 alo = *reinterpret_cast<const bf16x8*>(&Hs[pp][1][r][ks * 32 + g * 8]);
      acc = __builtin_amdgcn_mfma_f32_16x16x32_bf16(ahi[ks], bh[ks], acc, 0, 0, 0);
      acc = __builtin_amdgcn_mfma_f32_16x16x32_bf16(alo, bh[ks], acc, 0, 0, 0);
      acc = __builtin_amdgcn_mfma_f32_16x16x32_bf16(ahi[ks], bl[ks], acc, 0, 0, 0);
    }

    const int col = wv * 16 + r;
#pragma unroll
    for (int q = 0; q < 4; ++q) {
      const float v = fmaxf(acc[q], 0.f);
      const int row = 4 * g + q;
      const short hi = f2bf(v);
      Hs[pp ^ 1][0][row][col] = hi;
      Hs[pp ^ 1][1][row][col] = f2bf(v - bf2f(hi));
    }
    __syncthreads();
    pp ^= 1;
  }

  // layer 3: one 16x16 tile (cols 10..15 zero-padded), wave 0 only
  if (wv == 0) {
    const float bv = (r < 10) ? b3[r] : 0.f;
    f32x4 acc = {bv, bv, bv, bv};
    bf16x8 ahi[8], alo[8], bh[8], bl[8];
#pragma unroll
    for (int ks = 0; ks < 8; ++ks) {
      const int ko = ks * 32 + g * 8;
      ahi[ks] = *reinterpret_cast<const bf16x8*>(&Hs[pp][0][r][ko]);
      alo[ks] = *reinterpret_cast<const bf16x8*>(&Hs[pp][1][r][ko]);
      bh[ks] = *reinterpret_cast<const bf16x8*>(wf + 262144 + (ks << 9) + lane * 8);
      bl[ks] = *reinterpret_cast<const bf16x8*>(wf + 262144 + 4096 + (ks << 9) + lane * 8);
    }
#pragma unroll
    for (int ks = 0; ks < 8; ++ks) {
      acc = __builtin_amdgcn_mfma_f32_16x16x32_bf16(ahi[ks], bh[ks], acc, 0, 0, 0);
      acc = __builtin_amdgcn_mfma_f32_16x16x32_bf16(alo[ks], bh[ks], acc, 0, 0, 0);
      acc = __builtin_amdgcn_mfma_f32_16x16x32_bf16(ahi[ks], bl[ks], acc, 0, 0, 0);
    }
    if (r < 10) {
#pragma unroll
      for (int q = 0; q < 4; ++q)
        out[(size_t)(m0 + 4 * g + q) * 10 + r] = acc[q];
    }
  }
}

extern "C" void kernel_launch(void* const* d_in, const int* in_sizes, int n_in,
                              void* d_out, int out_size, void* d_ws, size_t ws_size,
                              hipStream_t stream) {
  const float* x   = (const float*)d_in[0];
  const float* cw0 = (const float*)d_in[1];
  const float* cw1 = (const float*)d_in[2];
  const float* cb  = (const float*)d_in[3];
  const float* w1  = (const float*)d_in[4];
  const float* b1  = (const float*)d_in[5];
  const float* w2  = (const float*)d_in[6];
  const float* b2  = (const float*)d_in[7];
  const float* w3  = (const float*)d_in[8];
  const float* b3  = (const float*)d_in[9];
  float* out = (float*)d_out;

  uint* h0p = (uint*)d_ws;             // 1 MB packed hi|lo
  short* wfm = (short*)(h0p + 262144); // 540 KB frag-linear weights

  conv_prep_kernel<<<512, 256, 0, stream>>>(x, cw0, cw1, cb, w1, w2, w3, h0p, wfm);
  mlp_fused<<<64, 1024, 0, stream>>>(h0p, wfm, b1, b2, b3, out);
}

// Round 19
// 27.949 us; speedup vs baseline: 1.2823x; 1.1476x over previous
//
#include <hip/hip_runtime.h>
#include <hip/hip_bf16.h>

#define NOBJ 25

typedef _Float16 f16x8 __attribute__((ext_vector_type(8)));
typedef short s16x4 __attribute__((ext_vector_type(4)));
typedef float f32x4 __attribute__((ext_vector_type(4)));
typedef unsigned int uint;

__device__ __forceinline__ short f2h_s(float f) {
  _Float16 h = (_Float16)f;   // single v_cvt_f16_f32 (RTN)
  return *reinterpret_cast<short*>(&h);
}

// ---------------------------------------------------------------------------
// K1: 512 blocks (one 2-block/CU residency round). Each block:
//  (a) grid-strided share of MLP-weight prep -> SINGLE f16, fragment-linear:
//      layer L in {0,1} at L*65536: [nt][ks][lane][j] (idx=((nt*8+ks)<<9)+lane*8+j),
//      layer3 at 131072: [ks][lane][j], cols>=10 zero-padded. 135168 shorts.
//      value = w[(nt*16+(lane&15))*256 + ks*32 + (lane>>4)*8 + j]
//  (b) conv for samples 2*bid, 2*bid+1 — R18 structure, f16 MFMA
//      (mfma_f32_16x16x32_f16; same fragment geometry as bf16; single-instr
//      cvt replaces the 4-5-instr bf16 RTN sequence). h written single f16.
// ---------------------------------------------------------------------------
__global__ __launch_bounds__(256, 2) void conv_prep_kernel(
    const float* __restrict__ x,    // (1024, 25*64)
    const float* __restrict__ cw0,  // (256, 64)
    const float* __restrict__ cw1,  // (256, 64)
    const float* __restrict__ cb,   // (256)
    const float* __restrict__ w1, const float* __restrict__ w2,
    const float* __restrict__ w3,
    short* __restrict__ h0,         // (1024, 256) f16 bits
    short* __restrict__ wfm)        // 135168 shorts, fragment-linear f16
{
  __shared__ short xs[2][32][72];        // 9216 B (f16 bits)
  __shared__ float ab[4][2][NOBJ][68];   // 54400 B (per-wave scratch)

  const int t = threadIdx.x;
  const int lane = t & 63;
  const int wv = t >> 6;
  const int r = lane & 15;
  const int g = lane >> 4;
  const int n0 = blockIdx.x * 2;

  // ---- x staging first: cold HBM misses issued before anything else ----
  for (int s = 0; s < 2; ++s) {
    const float4* xg = reinterpret_cast<const float4*>(x + (size_t)(n0 + s) * (NOBJ * 64));
    for (int i = t; i < 400; i += 256) {
      float4 v = xg[i];
      s16x4 p;
      p.x = f2h_s(v.x); p.y = f2h_s(v.y); p.z = f2h_s(v.z); p.w = f2h_s(v.w);
      *reinterpret_cast<s16x4*>(&xs[s][i >> 4][(i & 15) * 4]) = p;
    }
  }

  // ---- inline prep share (single f16) ----
  for (int j = blockIdx.x * 256 + t; j < 135168; j += 512 * 256) {
    const float* w; int f, nt;
    const bool isw3 = (j >= 131072);
    if (!isw3) {
      w = (j >> 16) ? w2 : w1;
      f = j & 65535;
      nt = f >> 12;
    } else {
      f = j - 131072;  // 0..4095
      w = w3;
      nt = 0;
    }
    const int ks = (f >> 9) & 7;
    const int l  = (f >> 3) & 63;
    const int jj = f & 7;
    const int col = nt * 16 + (l & 15);
    const int k   = ks * 32 + (l >> 4) * 8 + jj;
    const float v = (isw3 && col >= 10) ? 0.f : w[col * 256 + k];
    wfm[j] = f2h_s(v);
  }

  // ---- conv W fragments (f16, single cvt per element) ----
  f16x8 Wf[2][4][2];  // [tap][ntile][kstep]
#pragma unroll
  for (int tap = 0; tap < 2; ++tap) {
    const float* wsrc = tap ? cw1 : cw0;
#pragma unroll
    for (int ntl = 0; ntl < 4; ++ntl)
#pragma unroll
      for (int ks = 0; ks < 2; ++ks) {
        const int ch = wv * 64 + ntl * 16 + r;
        const float* p = wsrc + ch * 64 + ks * 32 + g * 8;
        const float4 a = *reinterpret_cast<const float4*>(p);
        const float4 b = *reinterpret_cast<const float4*>(p + 4);
        f16x8 fr;
        fr[0] = (_Float16)a.x; fr[1] = (_Float16)a.y; fr[2] = (_Float16)a.z; fr[3] = (_Float16)a.w;
        fr[4] = (_Float16)b.x; fr[5] = (_Float16)b.y; fr[6] = (_Float16)b.z; fr[7] = (_Float16)b.w;
        Wf[tap][ntl][ks] = fr;
      }
  }
  float cbv[4];
#pragma unroll
  for (int ntl = 0; ntl < 4; ++ntl) cbv[ntl] = cb[wv * 64 + ntl * 16 + r];

  __syncthreads();

  for (int s = 0; s < 2; ++s) {
    f16x8 Xf[2][2];  // rows 25..31 garbage, outputs unread
#pragma unroll
    for (int mt = 0; mt < 2; ++mt)
#pragma unroll
      for (int ks = 0; ks < 2; ++ks)
        Xf[mt][ks] = *reinterpret_cast<const f16x8*>(&xs[s][mt * 16 + r][ks * 32 + g * 8]);

    f32x4 acc[2][2][4];  // [tap][mtile][ntile]
#pragma unroll
    for (int tap = 0; tap < 2; ++tap)
#pragma unroll
      for (int mt = 0; mt < 2; ++mt)
#pragma unroll
        for (int ntl = 0; ntl < 4; ++ntl) {
          f32x4 z = {0.f, 0.f, 0.f, 0.f};
          acc[tap][mt][ntl] = z;
        }

#pragma unroll
    for (int tap = 0; tap < 2; ++tap)
#pragma unroll
      for (int mt = 0; mt < 2; ++mt)
#pragma unroll
        for (int ntl = 0; ntl < 4; ++ntl)
#pragma unroll
          for (int ks = 0; ks < 2; ++ks)
            acc[tap][mt][ntl] = __builtin_amdgcn_mfma_f32_16x16x32_f16(
                Xf[mt][ks], Wf[tap][ntl][ks], acc[tap][mt][ntl], 0, 0, 0);

#pragma unroll
    for (int tap = 0; tap < 2; ++tap)
#pragma unroll
      for (int mt = 0; mt < 2; ++mt)
#pragma unroll
        for (int ntl = 0; ntl < 4; ++ntl) {
          const int cl = ntl * 16 + r;
          const int row0 = mt * 16 + g * 4;
          const float badd = (tap == 0) ? cbv[ntl] : 0.f;
#pragma unroll
          for (int q = 0; q < 4; ++q)
            if (row0 + q < NOBJ) ab[wv][tap][row0 + q][cl] = acc[tap][mt][ntl][q] + badd;
        }
    // same-wave LDS RAW ordered by lgkmcnt; ab wave-private -> no barrier

    float A[NOBJ], Bv[NOBJ];
#pragma unroll
    for (int i = 0; i < NOBJ; ++i) { A[i] = ab[wv][0][i][lane]; Bv[i] = ab[wv][1][i][lane]; }
    float hacc = 0.f;
#pragma unroll
    for (int d = 1; d < NOBJ; ++d) {
      float sd = 0.f;
#pragma unroll
      for (int i = 0; i + d < NOBJ; ++i) sd += fmaxf(A[i] + Bv[i + d], 0.f);
      hacc = __builtin_fmaf(sd, 1.0f / (float)(NOBJ - d), hacc);
    }
    h0[(size_t)(n0 + s) * 256 + t] = f2h_s(hacc * (1.0f / (float)(NOBJ - 1)));
  }
}

// ---------------------------------------------------------------------------
// K2: full 3-layer MLP, SINGLE f16 (A and B). 64 blocks x 1024 threads
// (16 waves = 4/SIMD). Per-CU weight stream halves vs hi/lo bf16 (264KB);
// 8 MFMAs/wave/layer. Wave wv owns one 16-col tile; Hs f16 ping-pong in LDS.
// ---------------------------------------------------------------------------
__global__ __launch_bounds__(1024, 4) void mlp_fused(
    const short* __restrict__ h0,   // (1024,256) f16 bits
    const short* __restrict__ wfm,  // fragment-linear f16 weights
    const float* __restrict__ b1, const float* __restrict__ b2,
    const float* __restrict__ b3,
    float* __restrict__ out)        // (1024, 10)
{
  __shared__ short Hs[2][16][272];  // [pp][row][k] f16 bits, 17408 B
  const int t = threadIdx.x, lane = t & 63, wv = t >> 6;
  const int r = lane & 15, g = lane >> 4;
  const int m0 = blockIdx.x * 16;

  // stage 16 rows (4096 shorts): thread t -> elements 4t..4t+3
  {
    const s16x4 v = reinterpret_cast<const s16x4*>(h0 + (size_t)m0 * 256)[t];
    *reinterpret_cast<s16x4*>(&Hs[0][t >> 6][(t & 63) * 4]) = v;
  }
  __syncthreads();

  int pp = 0;
  const float* bias[2] = {b1, b2};
#pragma unroll
  for (int L = 0; L < 2; ++L) {
    const short* wl = wfm + L * 65536;

    f16x8 bfr[8];
#pragma unroll
    for (int ks = 0; ks < 8; ++ks)
      bfr[ks] = *reinterpret_cast<const f16x8*>(wl + ((wv * 8 + ks) << 9) + lane * 8);

    const float bv = bias[L][wv * 16 + r];
    f32x4 acc = {bv, bv, bv, bv};
#pragma unroll
    for (int ks = 0; ks < 8; ++ks) {
      const f16x8 afr = *reinterpret_cast<const f16x8*>(&Hs[pp][r][ks * 32 + g * 8]);
      acc = __builtin_amdgcn_mfma_f32_16x16x32_f16(afr, bfr[ks], acc, 0, 0, 0);
    }

    const int col = wv * 16 + r;
#pragma unroll
    for (int q = 0; q < 4; ++q)
      Hs[pp ^ 1][4 * g + q][col] = f2h_s(fmaxf(acc[q], 0.f));
    __syncthreads();
    pp ^= 1;
  }

  // layer 3: one 16x16 tile (cols 10..15 zero-padded), wave 0 only
  if (wv == 0) {
    const float bv = (r < 10) ? b3[r] : 0.f;
    f32x4 acc = {bv, bv, bv, bv};
#pragma unroll
    for (int ks = 0; ks < 8; ++ks) {
      const f16x8 afr = *reinterpret_cast<const f16x8*>(&Hs[pp][r][ks * 32 + g * 8]);
      const f16x8 bfr = *reinterpret_cast<const f16x8*>(wfm + 131072 + (ks << 9) + lane * 8);
      acc = __builtin_amdgcn_mfma_f32_16x16x32_f16(afr, bfr, acc, 0, 0, 0);
    }
    if (r < 10) {
#pragma unroll
      for (int q = 0; q < 4; ++q)
        out[(size_t)(m0 + 4 * g + q) * 10 + r] = acc[q];
    }
  }
}

extern "C" void kernel_launch(void* const* d_in, const int* in_sizes, int n_in,
                              void* d_out, int out_size, void* d_ws, size_t ws_size,
                              hipStream_t stream) {
  const float* x   = (const float*)d_in[0];
  const float* cw0 = (const float*)d_in[1];
  const float* cw1 = (const float*)d_in[2];
  const float* cb  = (const float*)d_in[3];
  const float* w1  = (const float*)d_in[4];
  const float* b1  = (const float*)d_in[5];
  const float* w2  = (const float*)d_in[6];
  const float* b2  = (const float*)d_in[7];
  const float* w3  = (const float*)d_in[8];
  const float* b3  = (const float*)d_in[9];
  float* out = (float*)d_out;

  short* h0  = (short*)d_ws;           // 512 KB f16
  short* wfm = h0 + 262144;            // 264 KB f16 frag-linear weights

  conv_prep_kernel<<<512, 256, 0, stream>>>(x, cw0, cw1, cb, w1, w2, w3, h0, wfm);
  mlp_fused<<<64, 1024, 0, stream>>>(h0, wfm, b1, b2, b3, out);
}